// Round 1
// baseline (324.631 us; speedup 1.0000x reference)
//
#include <hip/hip_runtime.h>

#define OUTD 7
#define SRD 2
#define PD (OUTD * SRD)   // 14 sample coords per axis
#define NCH 256

__global__ __launch_bounds__(256)
void pooler_kernel(const float* __restrict__ f0,
                   const float* __restrict__ f1,
                   const float* __restrict__ f2,
                   const float* __restrict__ f3,
                   const float* __restrict__ boxes,
                   const int*   __restrict__ img_ids,
                   float* __restrict__ out)
{
    const int roi = blockIdx.x;
    const int t   = threadIdx.x;

    // ---- per-ROI uniform scalars (every thread computes; cheap, uniform) ----
    const float bx1 = boxes[roi * 4 + 0];
    const float by1 = boxes[roi * 4 + 1];
    const float bx2 = boxes[roi * 4 + 2];
    const float by2 = boxes[roi * 4 + 3];

    const float area = (bx2 - bx1) * (by2 - by1);
    const float s    = sqrtf(area);
    float lvlf = floorf(4.0f + log2f(s / 224.0f + 1e-6f));
    lvlf = fminf(fmaxf(lvlf, 2.0f), 5.0f);
    const int lvl = (int)lvlf - 2;   // 0..3

    const float scales[4] = {0.25f, 0.125f, 0.0625f, 0.03125f};
    const int   dims[4]   = {200, 100, 50, 25};
    const float* feats[4] = {f0, f1, f2, f3};

    const float scale = scales[lvl];
    const int H = dims[lvl];
    const int W = H;
    const int plane = H * W;
    const float* __restrict__ feat = feats[lvl];

    const int img = img_ids[roi];
    const float* __restrict__ base0 = feat + (size_t)img * NCH * (size_t)plane;

    const float x1 = bx1 * scale, y1 = by1 * scale;
    const float x2 = bx2 * scale, y2 = by2 * scale;
    const float roi_w = fmaxf(x2 - x1, 1.0f);
    const float roi_h = fmaxf(y2 - y1, 1.0f);
    const float bw = roi_w / (float)OUTD;
    const float bh = roi_h / (float)OUTD;

    // ---- separable sample-coordinate precompute into LDS ----
    __shared__ int   s_yo0[PD], s_yo1[PD];   // y0*W, y1*W
    __shared__ int   s_xo0[PD], s_xo1[PD];   // x0,   x1
    __shared__ float s_ly[PD],  s_lx[PD];
    __shared__ int   s_yv[PD],  s_xv[PD];

    if (t < PD) {
        const int i = t >> 1, j = t & 1;      // coord p = i*SR + j
        const float yg = y1 + (float)i * bh + ((float)j + 0.5f) * bh * 0.5f;
        const int v = (yg >= -1.0f) && (yg <= (float)H);
        const float y = fminf(fmaxf(yg, 0.0f), (float)(H - 1));
        const int y0 = (int)floorf(y);
        const int y1i = min(y0 + 1, H - 1);
        s_yo0[t] = y0 * W;
        s_yo1[t] = y1i * W;
        s_ly[t]  = y - (float)y0;
        s_yv[t]  = v;
    } else if (t < 2 * PD) {
        const int tt = t - PD;
        const int i = tt >> 1, j = tt & 1;
        const float xg = x1 + (float)i * bw + ((float)j + 0.5f) * bw * 0.5f;
        const int v = (xg >= -1.0f) && (xg <= (float)W);
        const float x = fminf(fmaxf(xg, 0.0f), (float)(W - 1));
        const int x0 = (int)floorf(x);
        const int x1i = min(x0 + 1, W - 1);
        s_xo0[tt] = x0;
        s_xo1[tt] = x1i;
        s_lx[tt]  = x - (float)x0;
        s_xv[tt]  = v;
    }
    __syncthreads();

    // ---- main loop: e = c*49 + bin, strided by blockDim (coalesced stores) ----
    float* __restrict__ outbase = out + (size_t)roi * NCH * (OUTD * OUTD);

    for (int e = t; e < NCH * OUTD * OUTD; e += 256) {
        const int c   = e / 49;
        const int bin = e - c * 49;
        const int ph  = bin / 7;
        const int pw  = bin - ph * 7;

        const float* __restrict__ fb = base0 + (size_t)c * plane;

        float acc = 0.0f;
#pragma unroll
        for (int sy = 0; sy < SRD; ++sy) {
            const int ys  = ph * SRD + sy;
            const int yo0 = s_yo0[ys];
            const int yo1 = s_yo1[ys];
            const float ly = s_ly[ys];
            const float hy = 1.0f - ly;
            const int yv  = s_yv[ys];
#pragma unroll
            for (int sx = 0; sx < SRD; ++sx) {
                const int xs = pw * SRD + sx;
                if (yv && s_xv[xs]) {
                    const int x0  = s_xo0[xs];
                    const int x1i = s_xo1[xs];
                    const float lx = s_lx[xs];
                    const float hx = 1.0f - lx;
                    const float v00 = fb[yo0 + x0];
                    const float v01 = fb[yo0 + x1i];
                    const float v10 = fb[yo1 + x0];
                    const float v11 = fb[yo1 + x1i];
                    acc += hy * (hx * v00 + lx * v01) + ly * (hx * v10 + lx * v11);
                }
            }
        }
        outbase[e] = acc * 0.25f;
    }
}

extern "C" void kernel_launch(void* const* d_in, const int* in_sizes, int n_in,
                              void* d_out, int out_size, void* d_ws, size_t ws_size,
                              hipStream_t stream) {
    const float* f0    = (const float*)d_in[0];
    const float* f1    = (const float*)d_in[1];
    const float* f2    = (const float*)d_in[2];
    const float* f3    = (const float*)d_in[3];
    const float* boxes = (const float*)d_in[4];
    const int*   ids   = (const int*)d_in[5];
    float* out = (float*)d_out;

    const int N = in_sizes[4] / 4;   // number of ROIs

    pooler_kernel<<<N, 256, 0, stream>>>(f0, f1, f2, f3, boxes, ids, out);
}